// Round 4
// baseline (961.910 us; speedup 1.0000x reference)
//
#include <hip/hip_runtime.h>
#include <cstdint>

#define M_DIM 16384
#define N_DIM 4096
#define K_DIM 4096

// GEMM: 256x256 block tile, BK=128. 8 waves as 4M x 2N (wave tile 64x128).
// A staged in LDS (3 x 32KB rotating bufs, staged 2 tiles ahead).
// B read DIRECTLY global->VGPR (qw is L1/L2-resident; waves sharing wn issue
// identical addresses -> L1 broadcast), 1 sub-phase read-ahead, ping-pong.
#define BM 256
#define BN 256
#define BK 128

typedef __attribute__((ext_vector_type(4))) int int32x4;
typedef __attribute__((ext_vector_type(4))) float f32x4;

#define GLLD16(g, l)                                              \
  __builtin_amdgcn_global_load_lds(                               \
      (const __attribute__((address_space(1))) void*)(g),         \
      (__attribute__((address_space(3))) void*)(l), 16, 0, 0)

// ---------------------------------------------------------------------------
// Fused quantization kernel. Blocks [0,16384): activations. Blocks
// [16384,20480): one weight row each (+ wsum -> cs/off). One launch instead
// of two; if this shows in rocprof top-5 (>gemm) we learn the quant side is
// the real remaining cost.
// ---------------------------------------------------------------------------
__global__ void quant_fused(const float* __restrict__ x,
                            const float* __restrict__ w,
                            const float* __restrict__ wscale,
                            const float* __restrict__ bias,
                            const float* __restrict__ sp,
                            const int* __restrict__ zpp,
                            int8_t* __restrict__ qx,
                            int8_t* __restrict__ qw,
                            float* __restrict__ cs,
                            float* __restrict__ off) {
  __shared__ int red[4];
  if (blockIdx.x < 16384) {
    // ---- activation path: 16 floats/thread, lane-contiguous NT loads ----
    const float s = sp[0];
    const int zp = zpp[0];
    const size_t b = (size_t)blockIdx.x * 1024;
    const f32x4* x4 = (const f32x4*)x;
    unsigned* q4 = (unsigned*)qx;
#pragma unroll
    for (int i = 0; i < 4; i++) {
      const size_t idx = b + (size_t)i * 256 + threadIdx.x;
      f32x4 v = __builtin_nontemporal_load(&x4[idx]);
      int q0 = min(127, max(-128, (int)rintf(v[0] / s) + zp));
      int q1 = min(127, max(-128, (int)rintf(v[1] / s) + zp));
      int q2 = min(127, max(-128, (int)rintf(v[2] / s) + zp));
      int q3 = min(127, max(-128, (int)rintf(v[3] / s) + zp));
      q4[idx] = (unsigned)(q0 & 255) | ((unsigned)(q1 & 255) << 8) |
                ((unsigned)(q2 & 255) << 16) | ((unsigned)(q3 & 255) << 24);
    }
  } else {
    // ---- weight path: one output channel per block ----
    const int n = blockIdx.x - 16384;
    const float ws = wscale[n];
    const float s = sp[0];
    const int zp = zpp[0];
    const f32x4* wr = (const f32x4*)(w + (size_t)n * K_DIM);
    unsigned* qr = (unsigned*)(qw + (size_t)n * K_DIM);
    int sum = 0;
#pragma unroll
    for (int it = 0; it < K_DIM / (256 * 4); it++) {
      const int idx = it * 256 + threadIdx.x;
      f32x4 v = __builtin_nontemporal_load(&wr[idx]);
      int q0 = min(127, max(-128, (int)rintf(v[0] / ws)));
      int q1 = min(127, max(-128, (int)rintf(v[1] / ws)));
      int q2 = min(127, max(-128, (int)rintf(v[2] / ws)));
      int q3 = min(127, max(-128, (int)rintf(v[3] / ws)));
      sum += q0 + q1 + q2 + q3;
      qr[idx] = (unsigned)(q0 & 255) | ((unsigned)(q1 & 255) << 8) |
                ((unsigned)(q2 & 255) << 16) | ((unsigned)(q3 & 255) << 24);
    }
#pragma unroll
    for (int o = 32; o > 0; o >>= 1) sum += __shfl_down(sum, o, 64);
    if ((threadIdx.x & 63) == 0) red[threadIdx.x >> 6] = sum;
    __syncthreads();
    if (threadIdx.x == 0) {
      const int tot = red[0] + red[1] + red[2] + red[3];
      const float c = s * ws;
      cs[n] = c;
      off[n] = bias[n] - (float)(zp * tot) * c;
    }
  }
}

// ---------------------------------------------------------------------------
// Kernel 3: int8 GEMM, LDS-traffic-minimized structure.
//
// Why: round-3 counters (MfmaUtil 46%, HBM 28%, conflicts 0) + arithmetic:
// old structure moved 256 KB/CU/K-tile through LDS (~3000 cy @ 85 B/cy) vs
// 2600 cy of MFMA, serialized by the 2-barrier phase lockstep -> ~45% util.
// This version: A-only in LDS with 2x dup (waves 4M x 2N): 64 KB read +
// 32 KB write = 96 KB/K-tile (~1130 cy) << MFMA 2600 cy -> MFMA-bound.
// B-fragments load global->VGPR (16 rows x 64 B segments per instr; 4 waves
// per wn issue identical addrs -> L1 broadcast; qw 16 MB L2/L3-resident).
//
// Schedule per K-tile (ONE barrier + ONE vmcnt, no sub-phase barriers —
// legal because the only LDS writes target buf[t+2], untouched by any read
// for 2 barriers):
//   STAGE(buf[t+2])                      // 4 glld, lands way before use
//   loadB(g1); MM(g0)                    // B 1 sub-phase ahead, ping-pong
//   LDA(buf[t+1]) -> af[other]           // ds_reads drain under MM(g1..g3)
//   loadB(g2); MM(g1)
//   loadB(g3); MM(g2)
//   loadB(g0, next tile); MM(g3)
//   VM(4)   // leaves newest 4 VMEM (last B grp); guarantees this iter's
//           // STAGE landed -> next iter's mid-iter LDA(buf[t+2-1]) is safe
//   BAR()   // all waves' stages landed before anyone reads them next iter
// A-side LDS swizzle: chunk c of row r at c ^ (r&7), inverse pre-applied to
// the glld global source (linear dest, rule 21); measured 0 conflicts in r3.
//
// Verified-invariant carryover (round-3 passing epilogue, term-by-term):
//  B-data row = base + nt*16 + fr with acc 2nd idx nt  -> here
//    row = wn*128 + (g*2+ntl)*16 + fr, nt = g*2+ntl in 0..7          OK
//  epilogue col = n0 + wn*128 + nt*16 + quad*4 + reg                 OK
//  A-data row = wm*64 + mtl*16 + fr, acc 1st idx mtl; epilogue row =
//    m0 + wm*64 + mt*16 + fr                                          OK
// ---------------------------------------------------------------------------
__global__ __launch_bounds__(512, 2) void gemm_i8(
    const int8_t* __restrict__ qx, const int8_t* __restrict__ qw,
    const float* __restrict__ cs, const float* __restrict__ off,
    float* __restrict__ out) {
  __shared__ __align__(16) int8_t lds[98304];  // 3 x 32 KB A bufs

  const int tid = threadIdx.x;
  const int lane = tid & 63;
  const int wave = tid >> 6;  // 0..7
  const int wm = wave >> 1;   // 0..3  (64 rows each)
  const int wn = wave & 1;    // 0..1  (128 cols each)

  // T1: XCD swizzle, nwg=1024 (%8==0 -> bijective)
  const int bid = blockIdx.x;
  const int swz = (bid & 7) * 128 + (bid >> 3);
  const int n0 = (swz & 15) * BN;
  const int m0 = (swz >> 4) * BM;

  int32x4 acc[4][8] = {};
  int32x4 afA[8], afB[8], bf0[4], bf1[4];

  const int fr = lane & 15;
  const int quad = lane >> 4;

  // ---- A stage: one per-lane source base; 4 glld at compile-time imms.
  // dest row j: wave*16 + (j&1)*8 + (lane>>3) + (j>>1)*128 (linear, = base +
  // lane*16); src row identical (+m0); chunk = (lane&7)^(row&7), row&7 =
  // (lane>>3)&7 invariant across the j-offsets {0,8,128,136}.
  const int8_t* pSA = qx + (size_t)(m0 + wave * 16 + (lane >> 3)) * K_DIM +
                      (((lane & 7) ^ ((lane >> 3) & 7)) * 16);
  const int dBase = wave * 2048 + lane * 16;

  // ---- A fragment read offsets: row = wm*64 + mtl*16 + fr, chunk
  // (ks*4+quad)^(fr&7) = (ks^(fr>>2&1))*4 + (quad^(fr&3)) -> two ks-bases.
  const int fb2 = (fr >> 2) & 1;
  const int aBase = (wm * 64 + fr) * 128 + ((quad ^ (fr & 3)) * 16);
  const int aB0 = aBase + fb2 * 64;        // ks=0
  const int aB1 = aBase + (1 ^ fb2) * 64;  // ks=1

  // ---- B per-lane voffset: row = wn*128 + ntl*16 + fr, col chunk
  // ks*64 + quad*16 (+ g*32 rows = g*131072 B, ntl*16 rows = 65536 B).
  const int8_t* qwB = qw + (size_t)n0 * K_DIM;
  const unsigned vB = (unsigned)((wn * 128 + fr) * K_DIM + quad * 16);

#define STAGE(offS, ktv)                                                  \
  do {                                                                    \
    GLLD16(pSA + (ktv), lds + (offS) + dBase);                            \
    GLLD16(pSA + (ktv) + 32768, lds + (offS) + dBase + 1024);             \
    GLLD16(pSA + (ktv) + 524288, lds + (offS) + dBase + 16384);           \
    GLLD16(pSA + (ktv) + 557056, lds + (offS) + dBase + 17408);           \
  } while (0)

#define LDA(offS, AF)                                                     \
  do {                                                                    \
    _Pragma("unroll") for (int mtl = 0; mtl < 4; mtl++) {                 \
      AF[mtl * 2 + 0] = *(const int32x4*)(lds + (offS) + aB0 + mtl * 2048); \
      AF[mtl * 2 + 1] = *(const int32x4*)(lds + (offS) + aB1 + mtl * 2048); \
    }                                                                     \
  } while (0)

#define LDBG(g, ktv, BF)                                                  \
  do {                                                                    \
    _Pragma("unroll") for (int ntl = 0; ntl < 2; ntl++)                   \
        _Pragma("unroll") for (int ks = 0; ks < 2; ks++)                  \
            BF[ntl * 2 + ks] = *(const int32x4*)(qwB +                    \
                (size_t)(vB + ntl * 65536u + (g) * 131072u + ks * 64u +   \
                         (unsigned)(ktv)));                               \
  } while (0)

#define MM(g, BF, AF)                                                      \
  do {                                                                    \
    _Pragma("unroll") for (int mtl = 0; mtl < 4; mtl++)                   \
        _Pragma("unroll") for (int ntl = 0; ntl < 2; ntl++) {             \
      acc[mtl][(g)*2 + ntl] = __builtin_amdgcn_mfma_i32_16x16x64_i8(      \
          BF[ntl * 2 + 0], AF[mtl * 2 + 0], acc[mtl][(g)*2 + ntl], 0, 0, 0); \
      acc[mtl][(g)*2 + ntl] = __builtin_amdgcn_mfma_i32_16x16x64_i8(      \
          BF[ntl * 2 + 1], AF[mtl * 2 + 1], acc[mtl][(g)*2 + ntl], 0, 0, 0); \
    }                                                                      \
  } while (0)

#define BAR() __builtin_amdgcn_s_barrier()
#define VM4() asm volatile("s_waitcnt vmcnt(4)" ::: "memory")
#define PRIO(x) __builtin_amdgcn_s_setprio(x)

#define BODY(AF_USE, AF_LD)                                               \
  do {                                                                    \
    STAGE(oS, (kt + 256) & (K_DIM - 1));                                  \
    LDBG(1, kt, bf1);                                                     \
    PRIO(1); MM(0, bf0, AF_USE); PRIO(0);                                 \
    LDA(oN, AF_LD);                                                       \
    LDBG(2, kt, bf0);                                                     \
    PRIO(1); MM(1, bf1, AF_USE); PRIO(0);                                 \
    LDBG(3, kt, bf1);                                                     \
    PRIO(1); MM(2, bf0, AF_USE); PRIO(0);                                 \
    LDBG(0, (kt + 128) & (K_DIM - 1), bf0);                               \
    PRIO(1); MM(3, bf1, AF_USE); PRIO(0);                                 \
    VM4();                                                                \
    BAR();                                                                \
    {                                                                     \
      const int tmp = oC; oC = oN; oN = oS; oS = tmp;                     \
    }                                                                     \
    kt = (kt + 128) & (K_DIM - 1);                                        \
  } while (0)

  int oC = 0, oN = 32768, oS = 65536;
  int kt = 0;

  // ---- prologue: tiles 0,1 -> buf0,buf1; B g0; drain all glld (VM(4)
  // leaves exactly the 4 B loads); barrier -> every wave's stage visible.
  STAGE(0, 0);
  STAGE(32768, 128);
  LDBG(0, 0, bf0);
  VM4();
  BAR();
  LDA(0, afA);

  for (int t = 0; t < K_DIM / BK; t += 2) {
    BODY(afA, afB);
    BODY(afB, afA);
  }

  // ---- epilogue: lane holds 4 consecutive N-cols per tile -> f32x4 NT
  // stores (out never re-read).
#pragma unroll
  for (int nt = 0; nt < 8; nt++) {
    const int colb = n0 + wn * 128 + nt * 16 + quad * 4;
    const f32x4 c4 = *(const f32x4*)(cs + colb);
    const f32x4 o4 = *(const f32x4*)(off + colb);
#pragma unroll
    for (int mt = 0; mt < 4; mt++) {
      const int row = m0 + wm * 64 + mt * 16 + fr;
      f32x4 v;
      v[0] = (float)acc[mt][nt][0] * c4[0] + o4[0];
      v[1] = (float)acc[mt][nt][1] * c4[1] + o4[1];
      v[2] = (float)acc[mt][nt][2] * c4[2] + o4[2];
      v[3] = (float)acc[mt][nt][3] * c4[3] + o4[3];
      __builtin_nontemporal_store(
          v, (f32x4*)(out + (size_t)row * N_DIM + colb));
    }
  }
#undef STAGE
#undef LDA
#undef LDBG
#undef MM
#undef BAR
#undef VM4
#undef PRIO
#undef BODY
}

// ---------------------------------------------------------------------------
extern "C" void kernel_launch(void* const* d_in, const int* in_sizes, int n_in,
                              void* d_out, int out_size, void* d_ws,
                              size_t ws_size, hipStream_t stream) {
  const float* x = (const float*)d_in[0];
  const float* w = (const float*)d_in[1];
  const float* bias = (const float*)d_in[2];
  const float* act_scale = (const float*)d_in[3];
  const int* zp = (const int*)d_in[4];
  const float* wscale = (const float*)d_in[5];
  float* out = (float*)d_out;

  int8_t* qx = (int8_t*)d_ws;                          // 64 MB
  int8_t* qw = qx + (size_t)M_DIM * K_DIM;             // 16 MB
  float* cs = (float*)(qw + (size_t)N_DIM * K_DIM);    // 16 KB
  float* off = cs + N_DIM;                             // 16 KB

  quant_fused<<<16384 + N_DIM, 256, 0, stream>>>(x, w, wscale, bias,
                                                 act_scale, zp, qx, qw, cs,
                                                 off);
  gemm_i8<<<dim3((M_DIM / BM) * (N_DIM / BN)), 512, 0, stream>>>(qx, qw, cs,
                                                                 off, out);
}

// Round 5
// 661.331 us; speedup vs baseline: 1.4545x; 1.4545x over previous
//
#include <hip/hip_runtime.h>
#include <cstdint>

#define M_DIM 16384
#define N_DIM 4096
#define K_DIM 4096

// 256x256 tile, BK=128 int8 (128B rows), 8 waves (2M x 4N), 4-window schedule.
#define BM 256
#define BN 256
#define BK 128

typedef __attribute__((ext_vector_type(4))) int int32x4;
typedef __attribute__((ext_vector_type(4))) float f32x4;

#define GLLD16(g, l)                                              \
  __builtin_amdgcn_global_load_lds(                               \
      (const __attribute__((address_space(1))) void*)(g),         \
      (__attribute__((address_space(3))) void*)(l), 16, 0, 0)

// ---------------------------------------------------------------------------
// Fused quantization kernel. Blocks [0,16384): activations; [16384,20480):
// one weight row each (+ wsum -> cs/off). Reciprocal hoisted (1/s, 1/ws are
// wave-uniform): avoids the ~10-instr fp-div sequence per element.
// ---------------------------------------------------------------------------
__global__ void quant_fused(const float* __restrict__ x,
                            const float* __restrict__ w,
                            const float* __restrict__ wscale,
                            const float* __restrict__ bias,
                            const float* __restrict__ sp,
                            const int* __restrict__ zpp,
                            int8_t* __restrict__ qx,
                            int8_t* __restrict__ qw,
                            float* __restrict__ cs,
                            float* __restrict__ off) {
  __shared__ int red[4];
  if (blockIdx.x < 16384) {
    const float rs = 1.0f / sp[0];
    const int zp = zpp[0];
    const size_t b = (size_t)blockIdx.x * 1024;
    const f32x4* x4 = (const f32x4*)x;
    unsigned* q4 = (unsigned*)qx;
#pragma unroll
    for (int i = 0; i < 4; i++) {
      const size_t idx = b + (size_t)i * 256 + threadIdx.x;
      f32x4 v = __builtin_nontemporal_load(&x4[idx]);
      int q0 = min(127, max(-128, (int)rintf(v[0] * rs) + zp));
      int q1 = min(127, max(-128, (int)rintf(v[1] * rs) + zp));
      int q2 = min(127, max(-128, (int)rintf(v[2] * rs) + zp));
      int q3 = min(127, max(-128, (int)rintf(v[3] * rs) + zp));
      q4[idx] = (unsigned)(q0 & 255) | ((unsigned)(q1 & 255) << 8) |
                ((unsigned)(q2 & 255) << 16) | ((unsigned)(q3 & 255) << 24);
    }
  } else {
    const int n = blockIdx.x - 16384;
    const float ws = wscale[n];
    const float rws = 1.0f / ws;
    const float s = sp[0];
    const int zp = zpp[0];
    const f32x4* wr = (const f32x4*)(w + (size_t)n * K_DIM);
    unsigned* qr = (unsigned*)(qw + (size_t)n * K_DIM);
    int sum = 0;
#pragma unroll
    for (int it = 0; it < K_DIM / (256 * 4); it++) {
      const int idx = it * 256 + threadIdx.x;
      f32x4 v = __builtin_nontemporal_load(&wr[idx]);
      int q0 = min(127, max(-128, (int)rintf(v[0] * rws)));
      int q1 = min(127, max(-128, (int)rintf(v[1] * rws)));
      int q2 = min(127, max(-128, (int)rintf(v[2] * rws)));
      int q3 = min(127, max(-128, (int)rintf(v[3] * rws)));
      sum += q0 + q1 + q2 + q3;
      qr[idx] = (unsigned)(q0 & 255) | ((unsigned)(q1 & 255) << 8) |
                ((unsigned)(q2 & 255) << 16) | ((unsigned)(q3 & 255) << 24);
    }
#pragma unroll
    for (int o = 32; o > 0; o >>= 1) sum += __shfl_down(sum, o, 64);
    if ((threadIdx.x & 63) == 0) red[threadIdx.x >> 6] = sum;
    __syncthreads();
    if (threadIdx.x == 0) {
      const int tot = red[0] + red[1] + red[2] + red[3];
      const float c = s * ws;
      cs[n] = c;
      off[n] = bias[n] - (float)(zp * tot) * c;
    }
  }
}

// ---------------------------------------------------------------------------
// Kernel 3: int8 GEMM. Round-3 verified structure (LDS layout, T1/T2
// swizzles, fragment offsets, epilogue all byte-identical) with the 8-phase
// K-loop merged into 4 WINDOWS of 32 MFMAs each: 4 barriers + 4 vmcnt(8)
// per iter instead of 16 barriers + 2 vmcnt. Rationale: round-3 PMC showed
// MfmaUtil 46% with ~3400 cy/iter of sync overhead (16 barrier resyncs + 8
// lgkm tails); MM clusters of 16 MFMAs (~80 cy issue) can't amortize that.
//
// Window layout per iter (2 K-tiles: e=2i in buf0, o=2i+1 in buf1):
//   W1: read buf0.{A.h0,B.h0,B.h1}; MM(0,0)+MM(0,1); stage buf1.A.h1<-t2i+1
//   W2: read buf0.A.h1;             MM(1,1)+MM(1,0); stage buf0.{A.h0,B.h0,B.h1}<-t2i+2
//   W3: read buf1.{A.h0,B.h0,B.h1}; MM(0,0)+MM(0,1); stage buf0.A.h1<-t2i+2
//   W4: read buf1.A.h1;             MM(1,1)+MM(1,0); stage buf1.{A.h0,B.h0,B.h1}<-t2i+3
// Hazard ledger (stage S vs read R of same region, must be >=1 barrier
// apart): W1.stage(buf1.A.h1) vs R@W4 prev-iter: 1 bar  OK (reads drained at
// W4's lgkmcnt before its end-bar). W2.stages vs R@W1: 1 bar OK. W3.stage
// (buf0.A.h1) vs R@W2: 1 bar OK. W4.stages vs R@W3: 1 bar OK.
// vmcnt ledger (2,6,2,6 glld per window; reads of W need stages from 3
// windows back landed): uniform VM(8) at every window end drains exactly the
// 3-windows-old group each time:
//   end-W1: out=prevW3(2)+prevW4(6)+W1(2)=10 -> drains prevW3 (W2's A.h1) OK
//   end-W2: out=prevW4(6)+W1(2)+W2(6)=14 -> drains prevW4 (W3's buf1 rgns) OK
//   end-W3: out=W1(2)+W2(6)+W3(2)=10 -> drains W1 (W4's buf1.A.h1) OK
//   end-W4: out=W2(6)+W3(2)+W4(6)=14 -> drains W2 (next-W1's buf0 rgns) OK
// Prologue stages buf0+buf1 fully (16 glld), VM(8) drains buf0; first-iter
// W1 re-stages buf1.A.h1 with identical bytes (harmless).
// ---------------------------------------------------------------------------
__global__ __launch_bounds__(512, 2) void gemm_i8(
    const int8_t* __restrict__ qx, const int8_t* __restrict__ qw,
    const float* __restrict__ cs, const float* __restrict__ off,
    float* __restrict__ out) {
  __shared__ __align__(16) int8_t lds[131072];

  const int tid = threadIdx.x;
  const int lane = tid & 63;
  const int wave = tid >> 6;  // 0..7
  const int wm = wave >> 2;   // 0..1  (128 rows each)
  const int wn = wave & 3;    // 0..3  (64 cols each)

  // T1: XCD-aware swizzle, nwg=1024 (%8==0 -> bijective)
  const int bid = blockIdx.x;
  const int swz = (bid & 7) * 128 + (bid >> 3);
  const int n0 = (swz & 15) * BN;
  const int m0 = (swz >> 4) * BM;

  int32x4 acc[8][4] = {};
  int32x4 af[8], bf0[4], bf1[4];

  // ---- staging source pointers (2 glld per wave per half; lane-linear LDS
  // dest; inverse-swizzled global source) ----
  const int scol = ((lane & 7) ^ ((lane >> 3) & 7)) * 16;
  const int8_t* pA[2][2];
  const int8_t* pB[2][2];
#pragma unroll
  for (int h = 0; h < 2; h++)
#pragma unroll
    for (int j = 0; j < 2; j++) {
      const int r = h * 128 + (wave * 2 + j) * 8 + (lane >> 3);  // lds row
      const int ga = ((r >> 6) & 1) * 128 + (r >> 7) * 64 + (r & 63);
      const int gb = ((r >> 5) & 3) * 64 + (r >> 7) * 32 + (r & 31);
      pA[h][j] = qx + (size_t)(m0 + ga) * K_DIM + scol;
      pB[h][j] = qw + (size_t)(n0 + gb) * K_DIM + scol;
    }

  // ---- fragment read offsets (h=0 / g=0; +16384 per half) ----
  const int fr = lane & 15;
  const int quad = lane >> 4;
  int aoffs[8], boffs[4];
#pragma unroll
  for (int mtl = 0; mtl < 4; mtl++)
#pragma unroll
    for (int ks = 0; ks < 2; ks++) {
      const int r = wm * 64 + mtl * 16 + fr;
      const int c = (ks * 4 + quad) ^ (fr & 7);
      aoffs[mtl * 2 + ks] = r * 128 + c * 16;
    }
#pragma unroll
  for (int ntl = 0; ntl < 2; ntl++)
#pragma unroll
    for (int ks = 0; ks < 2; ks++) {
      const int r = wn * 32 + ntl * 16 + fr;
      const int c = (ks * 4 + quad) ^ (fr & 7);
      boffs[ntl * 2 + ks] = r * 128 + c * 16;
    }

#define STAGE(rbase, h, P, kb)                                          \
  do {                                                                  \
    GLLD16(P[h][0] + (kb), lds + (rbase) + (h) * 16384 + wave * 2048);  \
    GLLD16(P[h][1] + (kb),                                              \
           lds + (rbase) + (h) * 16384 + wave * 2048 + 1024);           \
  } while (0)

#define LDA(buf, h)                                                     \
  do {                                                                  \
    _Pragma("unroll") for (int q = 0; q < 8; q++) af[q] =               \
        *(const int32x4*)(lds + (buf) * 65536 + (h) * 16384 + aoffs[q]); \
  } while (0)

#define LDB(buf, g, BF)                                                 \
  do {                                                                  \
    _Pragma("unroll") for (int q = 0; q < 4; q++) BF[q] =               \
        *(const int32x4*)(lds + (buf) * 65536 + 32768 + (g) * 16384 +   \
                          boffs[q]);                                    \
  } while (0)

// Swapped operands (verified r3): A-op = qw frag (lane dim -> D reg = N),
// B-op = qx frag (lane dim -> D lane = M).
#define MM(h, g, BF)                                                       \
  do {                                                                    \
    _Pragma("unroll") for (int mtl = 0; mtl < 4; mtl++)                   \
        _Pragma("unroll") for (int ntl = 0; ntl < 2; ntl++) {             \
      acc[(h)*4 + mtl][(g)*2 + ntl] = __builtin_amdgcn_mfma_i32_16x16x64_i8( \
          BF[ntl * 2 + 0], af[mtl * 2 + 0], acc[(h)*4 + mtl][(g)*2 + ntl], \
          0, 0, 0);                                                        \
      acc[(h)*4 + mtl][(g)*2 + ntl] = __builtin_amdgcn_mfma_i32_16x16x64_i8( \
          BF[ntl * 2 + 1], af[mtl * 2 + 1], acc[(h)*4 + mtl][(g)*2 + ntl], \
          0, 0, 0);                                                        \
    }                                                                      \
  } while (0)

#define BAR() __builtin_amdgcn_s_barrier()
#define WAITLGKM() asm volatile("s_waitcnt lgkmcnt(0)" ::: "memory")
#define VM8() asm volatile("s_waitcnt vmcnt(8)" ::: "memory")
#define PRIO(x) __builtin_amdgcn_s_setprio(x)

  // ---- prologue: tile0 -> buf0 (8 glld), tile1 -> buf1 (8 glld);
  // VM(8) drains buf0's 8 -> W1/W2 reads safe; buf1 drains via W2's VM8.
  STAGE(0, 0, pA, 0);
  STAGE(0, 1, pA, 0);
  STAGE(32768, 0, pB, 0);
  STAGE(32768, 1, pB, 0);
  STAGE(65536, 0, pA, 128);
  STAGE(65536, 1, pA, 128);
  STAGE(98304, 0, pB, 128);
  STAGE(98304, 1, pB, 128);
  VM8();
  BAR();

  for (int i = 0; i < K_DIM / (2 * BK); i++) {
    const int kb1 = ((2 * i + 1) << 7) & (K_DIM - 1);
    const int kb2 = ((2 * i + 2) << 7) & (K_DIM - 1);
    const int kb3 = ((2 * i + 3) << 7) & (K_DIM - 1);
    // ---- W1: tile e, h0 x {g0,g1} ----
    LDA(0, 0);
    LDB(0, 0, bf0);
    LDB(0, 1, bf1);
    WAITLGKM();
    PRIO(1); MM(0, 0, bf0); PRIO(0);
    STAGE(65536, 1, pA, kb1);  // buf1.A.h1 <- t(2i+1)
    PRIO(1); MM(0, 1, bf1); PRIO(0);
    VM8();
    BAR();
    // ---- W2: tile e, h1 x {g1,g0} ----
    LDA(0, 1);
    WAITLGKM();
    PRIO(1); MM(1, 1, bf1); PRIO(0);
    STAGE(0, 0, pA, kb2);      // buf0.A.h0 <- t(2i+2)
    STAGE(32768, 0, pB, kb2);  // buf0.B.h0
    STAGE(32768, 1, pB, kb2);  // buf0.B.h1
    PRIO(1); MM(1, 0, bf0); PRIO(0);
    VM8();
    BAR();
    // ---- W3: tile o, h0 x {g0,g1} ----
    LDA(1, 0);
    LDB(1, 0, bf0);
    LDB(1, 1, bf1);
    WAITLGKM();
    PRIO(1); MM(0, 0, bf0); PRIO(0);
    STAGE(0, 1, pA, kb2);      // buf0.A.h1 <- t(2i+2)
    PRIO(1); MM(0, 1, bf1); PRIO(0);
    VM8();
    BAR();
    // ---- W4: tile o, h1 x {g1,g0} ----
    LDA(1, 1);
    WAITLGKM();
    PRIO(1); MM(1, 1, bf1); PRIO(0);
    STAGE(65536, 0, pA, kb3);  // buf1.A.h0 <- t(2i+3)
    STAGE(98304, 0, pB, kb3);  // buf1.B.h0
    STAGE(98304, 1, pB, kb3);  // buf1.B.h1
    PRIO(1); MM(1, 0, bf0); PRIO(0);
    VM8();
    BAR();
  }

  // ---- epilogue (verified r3): lane holds 4 consecutive N-cols per tile ->
  // f32x4 NT stores. n = colb + reg, m = row-base + fr (lane).
#pragma unroll
  for (int nt = 0; nt < 4; nt++) {
    const int colb = n0 + wn * 64 + nt * 16 + quad * 4;
    const f32x4 c4 = *(const f32x4*)(cs + colb);
    const f32x4 o4 = *(const f32x4*)(off + colb);
#pragma unroll
    for (int mt = 0; mt < 8; mt++) {
      const int row = m0 + wm * 128 + mt * 16 + fr;
      f32x4 v;
      v[0] = (float)acc[mt][nt][0] * c4[0] + o4[0];
      v[1] = (float)acc[mt][nt][1] * c4[1] + o4[1];
      v[2] = (float)acc[mt][nt][2] * c4[2] + o4[2];
      v[3] = (float)acc[mt][nt][3] * c4[3] + o4[3];
      __builtin_nontemporal_store(
          v, (f32x4*)(out + (size_t)row * N_DIM + colb));
    }
  }
#undef STAGE
#undef LDA
#undef LDB
#undef MM
#undef BAR
#undef WAITLGKM
#undef VM8
#undef PRIO
}

// ---------------------------------------------------------------------------
extern "C" void kernel_launch(void* const* d_in, const int* in_sizes, int n_in,
                              void* d_out, int out_size, void* d_ws,
                              size_t ws_size, hipStream_t stream) {
  const float* x = (const float*)d_in[0];
  const float* w = (const float*)d_in[1];
  const float* bias = (const float*)d_in[2];
  const float* act_scale = (const float*)d_in[3];
  const int* zp = (const int*)d_in[4];
  const float* wscale = (const float*)d_in[5];
  float* out = (float*)d_out;

  int8_t* qx = (int8_t*)d_ws;                          // 64 MB
  int8_t* qw = qx + (size_t)M_DIM * K_DIM;             // 16 MB
  float* cs = (float*)(qw + (size_t)N_DIM * K_DIM);    // 16 KB
  float* off = cs + N_DIM;                             // 16 KB

  quant_fused<<<16384 + N_DIM, 256, 0, stream>>>(x, w, wscale, bias,
                                                 act_scale, zp, qx, qw, cs,
                                                 off);
  gemm_i8<<<dim3((M_DIM / BM) * (N_DIM / BN)), 512, 0, stream>>>(qx, qw, cs,
                                                                 off, out);
}